// Round 5
// baseline (449.295 us; speedup 1.0000x reference)
//
#include <hip/hip_runtime.h>
#include <cstdint>
#include <cstddef>

// Problem constants
#define B_    8
#define S_    2048
#define DM_   512
#define H_    8
#define SD_   64
#define HID_  2048
#define ROWS  (B_*S_)      // 16384
#define BH    (B_*H_)      // 64
#define NCHUNK 32
#define CLEN   64
#define EPS_  1e-5f

typedef __bf16 bf16x8 __attribute__((ext_vector_type(8)));
typedef float  floatx4 __attribute__((ext_vector_type(4)));

// ---------- small helpers ----------
static __device__ __forceinline__ float bf2f(unsigned short h){
  union { unsigned int u; float f; } v; v.u = ((unsigned int)h) << 16; return v.f;
}
static __device__ __forceinline__ unsigned short f2bf(float f){
  union { float f; unsigned int u; } v; v.f = f;
  unsigned int r = v.u + 0x7fffu + ((v.u >> 16) & 1u);
  return (unsigned short)(r >> 16);
}
static __device__ __forceinline__ float fast_tanh(float x){
  float ax = fabsf(x);
  float e  = __expf(2.f*ax);
  float t  = 1.f - 2.f/(e+1.f);
  return copysignf(t, x);
}
static __device__ __forceinline__ float sigmoidf_(float z){
  return 1.f/(1.f + expf(-z));
}
static __device__ __forceinline__ float gelu_exact(float x){
  return 0.5f*x*(1.f + erff(x*0.70710678118654752440f));
}
static __device__ __forceinline__ void gld_lds16(const unsigned short* g, unsigned short* lds){
  __builtin_amdgcn_global_load_lds(
      (const __attribute__((address_space(1))) void*)g,
      (__attribute__((address_space(3))) void*)lds,
      16, 0, 0);
}
// XOR swizzle for 64-half (128B) rows: 16B chunk kc of row r stored at chunk kc^(r&7)
static __device__ __forceinline__ int swz(int row, int col){
  return row*64 + (((col>>3) ^ (row&7))<<3) + (col&7);
}

// ---------- weight fp32 -> bf16 conversion ----------
__global__ __launch_bounds__(256) void cvt_weights(
    const float* __restrict__ wa, const float* __restrict__ wb,
    const float* __restrict__ wql, const float* __restrict__ wqr,
    const float* __restrict__ wout, const float* __restrict__ w1,
    const float* __restrict__ w2,
    unsigned short* __restrict__ wcat, unsigned short* __restrict__ woutb,
    unsigned short* __restrict__ w1b, unsigned short* __restrict__ w2b){
  int i = blockIdx.x*256 + threadIdx.x;   // float4 units, total 851968
  const float* s; unsigned short* d; int base;
  if      (i <  65536){ s=wa;   d=wcat;          base=i; }
  else if (i < 131072){ s=wb;   d=wcat+262144;   base=i-65536; }
  else if (i < 196608){ s=wql;  d=wcat+524288;   base=i-131072; }
  else if (i < 262144){ s=wqr;  d=wcat+786432;   base=i-196608; }
  else if (i < 327680){ s=wout; d=woutb;         base=i-262144; }
  else if (i < 589824){ s=w1;   d=w1b;           base=i-327680; }
  else                { s=w2;   d=w2b;           base=i-589824; }
  float4 v = ((const float4*)s)[base];
  ushort4 o; o.x=f2bf(v.x); o.y=f2bf(v.y); o.z=f2bf(v.z); o.w=f2bf(v.w);
  ((ushort4*)d)[base] = o;
}

// ---------- LN1 + gate heads ----------
__global__ __launch_bounds__(64) void ln_gates(
    const float* __restrict__ x, const float* __restrict__ gam, const float* __restrict__ bet,
    const float* __restrict__ Wsd, const float* __restrict__ bsd,
    const float* __restrict__ Wpd, const float* __restrict__ bpd,
    unsigned short* __restrict__ nbf, float* __restrict__ sdo, float* __restrict__ pdo){
  const int row = blockIdx.x, l = threadIdx.x;
  const float* xr = x + (size_t)row*DM_;
  float4 v0 = ((const float4*)xr)[l*2];
  float4 v1 = ((const float4*)xr)[l*2+1];
  float v[8] = {v0.x,v0.y,v0.z,v0.w,v1.x,v1.y,v1.z,v1.w};
  float s = 0.f;
  #pragma unroll
  for (int i=0;i<8;++i) s += v[i];
  #pragma unroll
  for (int m=1;m<64;m<<=1) s += __shfl_xor(s, m);
  const float mean = s * (1.f/512.f);
  float q = 0.f;
  #pragma unroll
  for (int i=0;i<8;++i){ float d = v[i]-mean; q += d*d; }
  #pragma unroll
  for (int m=1;m<64;m<<=1) q += __shfl_xor(q, m);
  const float rstd = rsqrtf(q*(1.f/512.f) + EPS_);
  float4 g0 = ((const float4*)gam)[l*2], g1 = ((const float4*)gam)[l*2+1];
  float4 b0 = ((const float4*)bet)[l*2], b1 = ((const float4*)bet)[l*2+1];
  float gg[8] = {g0.x,g0.y,g0.z,g0.w,g1.x,g1.y,g1.z,g1.w};
  float bb[8] = {b0.x,b0.y,b0.z,b0.w,b1.x,b1.y,b1.z,b1.w};
  float n[8];
  #pragma unroll
  for (int i=0;i<8;++i) n[i] = (v[i]-mean)*rstd*gg[i] + bb[i];
  ushort4 o0, o1;
  o0.x=f2bf(n[0]); o0.y=f2bf(n[1]); o0.z=f2bf(n[2]); o0.w=f2bf(n[3]);
  o1.x=f2bf(n[4]); o1.y=f2bf(n[5]); o1.z=f2bf(n[6]); o1.w=f2bf(n[7]);
  ((ushort4*)(nbf + (size_t)row*DM_))[l*2]   = o0;
  ((ushort4*)(nbf + (size_t)row*DM_))[l*2+1] = o1;
  float acc[16];
  #pragma unroll
  for (int hh=0; hh<8; ++hh){
    const float4* ws = (const float4*)(Wsd + hh*DM_) + l*2;
    const float4* wp = (const float4*)(Wpd + hh*DM_) + l*2;
    float4 a0=ws[0], a1=ws[1], p0=wp[0], p1=wp[1];
    acc[hh]   = n[0]*a0.x+n[1]*a0.y+n[2]*a0.z+n[3]*a0.w+n[4]*a1.x+n[5]*a1.y+n[6]*a1.z+n[7]*a1.w;
    acc[8+hh] = n[0]*p0.x+n[1]*p0.y+n[2]*p0.z+n[3]*p0.w+n[4]*p1.x+n[5]*p1.y+n[6]*p1.z+n[7]*p1.w;
  }
  #pragma unroll
  for (int k=0;k<16;++k){
    float a = acc[k];
    #pragma unroll
    for (int m=1;m<64;m<<=1) a += __shfl_xor(a, m);
    acc[k] = a;
  }
  if (l==0){
    #pragma unroll
    for (int hh=0; hh<8; ++hh){
      sdo[row*8+hh] = sigmoidf_(acc[hh]   + bsd[hh]);
      pdo[row*8+hh] = sigmoidf_(acc[8+hh] + bpd[hh]);
    }
  }
}

// ---------- plain LN (FFN), bf16 input ----------
__global__ __launch_bounds__(64) void ln_plain(
    const unsigned short* __restrict__ xb, const float* __restrict__ gam, const float* __restrict__ bet,
    unsigned short* __restrict__ ob){
  const int row = blockIdx.x, l = threadIdx.x;
  const unsigned short* xr = xb + (size_t)row*DM_ + l*8;
  ushort4 u0 = *(const ushort4*)xr;
  ushort4 u1 = *(const ushort4*)(xr+4);
  float v[8] = {bf2f(u0.x),bf2f(u0.y),bf2f(u0.z),bf2f(u0.w),
                bf2f(u1.x),bf2f(u1.y),bf2f(u1.z),bf2f(u1.w)};
  float s = 0.f;
  #pragma unroll
  for (int i=0;i<8;++i) s += v[i];
  #pragma unroll
  for (int m=1;m<64;m<<=1) s += __shfl_xor(s, m);
  const float mean = s * (1.f/512.f);
  float q = 0.f;
  #pragma unroll
  for (int i=0;i<8;++i){ float d = v[i]-mean; q += d*d; }
  #pragma unroll
  for (int m=1;m<64;m<<=1) q += __shfl_xor(q, m);
  const float rstd = rsqrtf(q*(1.f/512.f) + EPS_);
  float4 g0 = ((const float4*)gam)[l*2], g1 = ((const float4*)gam)[l*2+1];
  float4 b0 = ((const float4*)bet)[l*2], b1 = ((const float4*)bet)[l*2+1];
  float gg[8] = {g0.x,g0.y,g0.z,g0.w,g1.x,g1.y,g1.z,g1.w};
  float bb[8] = {b0.x,b0.y,b0.z,b0.w,b1.x,b1.y,b1.z,b1.w};
  ushort4 o0, o1;
  o0.x=f2bf((v[0]-mean)*rstd*gg[0]+bb[0]); o0.y=f2bf((v[1]-mean)*rstd*gg[1]+bb[1]);
  o0.z=f2bf((v[2]-mean)*rstd*gg[2]+bb[2]); o0.w=f2bf((v[3]-mean)*rstd*gg[3]+bb[3]);
  o1.x=f2bf((v[4]-mean)*rstd*gg[4]+bb[4]); o1.y=f2bf((v[5]-mean)*rstd*gg[5]+bb[5]);
  o1.z=f2bf((v[6]-mean)*rstd*gg[6]+bb[6]); o1.w=f2bf((v[7]-mean)*rstd*gg[7]+bb[7]);
  ((ushort4*)(ob + (size_t)row*DM_))[l*2]   = o0;
  ((ushort4*)(ob + (size_t)row*DM_))[l*2+1] = o1;
}

// ---------- 256x256-tile bf16 MFMA GEMM (8 waves), BK=64, swizzled staging ----------
// MODE 0: tanh -> bf16 (projections); MODE 2: +bias, gelu -> bf16 (FFN1)
template<int MODE>
__global__ __launch_bounds__(512, 2) void gemm256(
    const unsigned short* __restrict__ A, const unsigned short* __restrict__ W,
    const float* __restrict__ bias, unsigned short* __restrict__ outb,
    int N, int K){
  __shared__ __align__(16) unsigned short As[256*64];   // 32 KB
  __shared__ __align__(16) unsigned short Ws[256*64];   // 32 KB
  const int tid  = threadIdx.x;
  const int w    = tid >> 6;          // 0..7
  const int lane = tid & 63;
  const int mblk = blockIdx.x, nblk = blockIdx.y;
  const int mrow = (w >> 1) * 64;     // 0,64,128,192
  const int ncol = (w & 1) * 128;     // 0,128
  const int fr = lane & 15, fq = lane >> 4;

  int srow[4], scol[4];
  #pragma unroll
  for (int q=0;q<4;++q){
    const int p = q*512 + tid;        // 16B-chunk index, 0..2047
    srow[q] = p >> 3;
    scol[q] = ((p & 7) ^ (srow[q] & 7)) * 8;
  }

  floatx4 acc[4][8];
  #pragma unroll
  for (int i=0;i<4;++i)
    #pragma unroll
    for (int j=0;j<8;++j)
      acc[i][j] = (floatx4){0.f,0.f,0.f,0.f};

  for (int k0=0; k0<K; k0+=64){
    #pragma unroll
    for (int q=0;q<4;++q){
      gld_lds16(A + (size_t)(mblk*256 + srow[q])*K + k0 + scol[q], As + (q*512 + tid)*8);
      gld_lds16(W + (size_t)(nblk*256 + srow[q])*K + k0 + scol[q], Ws + (q*512 + tid)*8);
    }
    __syncthreads();
    #pragma unroll
    for (int kh=0;kh<2;++kh){
      bf16x8 af[4], bf[8];
      #pragma unroll
      for (int i=0;i<4;++i) af[i] = *(const bf16x8*)&As[swz(mrow + i*16 + fr, kh*32 + fq*8)];
      #pragma unroll
      for (int j=0;j<8;++j) bf[j] = *(const bf16x8*)&Ws[swz(ncol + j*16 + fr, kh*32 + fq*8)];
      #pragma unroll
      for (int i=0;i<4;++i)
        #pragma unroll
        for (int j=0;j<8;++j)
          acc[i][j] = __builtin_amdgcn_mfma_f32_16x16x32_bf16(af[i], bf[j], acc[i][j], 0, 0, 0);
    }
    __syncthreads();
  }

  #pragma unroll
  for (int i=0;i<4;++i){
    const int grow_base = mblk*256 + mrow + i*16 + fq*4;
    #pragma unroll
    for (int j=0;j<8;++j){
      const int gcol = nblk*256 + ncol + j*16 + fr;
      float bias_v = 0.f;
      if (MODE==2) bias_v = bias[gcol];
      #pragma unroll
      for (int r=0;r<4;++r){
        const size_t o = (size_t)(grow_base + r)*N + gcol;
        float v = acc[i][j][r];
        if (MODE==0) outb[o] = f2bf(fast_tanh(v));
        else         outb[o] = f2bf(gelu_exact(v + bias_v));
      }
    }
  }
}

// ---------- 128x128-tile GEMM for N=512 cases ----------
// MODE 1: + resid(f32) -> bf16 (Wout residual, writes r in bf16)
// MODE 3: + bias + resid(bf16) -> f32 (FFN2 / final output)
template<int MODE>
__global__ __launch_bounds__(256) void gemm128(
    const unsigned short* __restrict__ A, const unsigned short* __restrict__ W,
    const float* __restrict__ bias, const float* __restrict__ residf,
    const unsigned short* __restrict__ residb,
    float* __restrict__ outf, unsigned short* __restrict__ outb,
    int N, int K){
  __shared__ __align__(16) unsigned short As[128*64];
  __shared__ __align__(16) unsigned short Ws[128*64];
  const int tid  = threadIdx.x;
  const int w    = tid >> 6;
  const int lane = tid & 63;
  const int mblk = blockIdx.x, nblk = blockIdx.y;
  const int mrow = (w >> 1) * 64;
  const int ncol = (w & 1) * 64;
  const int fr = lane & 15, fq = lane >> 4;

  int srow[4], scol[4];
  #pragma unroll
  for (int q=0;q<4;++q){
    const int p = q*256 + w*64 + lane;
    srow[q] = p >> 3;
    scol[q] = ((p & 7) ^ (srow[q] & 7)) * 8;
  }

  floatx4 acc[4][4];
  #pragma unroll
  for (int i=0;i<4;++i)
    #pragma unroll
    for (int j=0;j<4;++j)
      acc[i][j] = (floatx4){0.f,0.f,0.f,0.f};

  for (int k0=0; k0<K; k0+=64){
    #pragma unroll
    for (int q=0;q<4;++q){
      gld_lds16(A + (size_t)(mblk*128 + srow[q])*K + k0 + scol[q], As + (q*256 + w*64)*8);
      gld_lds16(W + (size_t)(nblk*128 + srow[q])*K + k0 + scol[q], Ws + (q*256 + w*64)*8);
    }
    __syncthreads();
    #pragma unroll
    for (int kh=0;kh<2;++kh){
      bf16x8 af[4], bf[4];
      #pragma unroll
      for (int i=0;i<4;++i) af[i] = *(const bf16x8*)&As[swz(mrow + i*16 + fr, kh*32 + fq*8)];
      #pragma unroll
      for (int j=0;j<4;++j) bf[j] = *(const bf16x8*)&Ws[swz(ncol + j*16 + fr, kh*32 + fq*8)];
      #pragma unroll
      for (int i=0;i<4;++i)
        #pragma unroll
        for (int j=0;j<4;++j)
          acc[i][j] = __builtin_amdgcn_mfma_f32_16x16x32_bf16(af[i], bf[j], acc[i][j], 0, 0, 0);
    }
    __syncthreads();
  }

  #pragma unroll
  for (int i=0;i<4;++i){
    const int grow_base = mblk*128 + mrow + i*16 + fq*4;
    #pragma unroll
    for (int j=0;j<4;++j){
      const int gcol = nblk*128 + ncol + j*16 + fr;
      float bias_v = 0.f;
      if (MODE==3) bias_v = bias[gcol];
      #pragma unroll
      for (int r=0;r<4;++r){
        const size_t o = (size_t)(grow_base + r)*N + gcol;
        float v = acc[i][j][r];
        if (MODE==1) outb[o] = f2bf(residf[o] + v);
        else         outf[o] = bf2f(residb[o]) + v + bias_v;
      }
    }
  }
}

// ---------- state scan, chunk-local (bf16 sloc + f32 chunk ends) ----------
__global__ __launch_bounds__(64) void state_local(
    const unsigned short* __restrict__ proj, const float* __restrict__ sdo,
    unsigned short* __restrict__ slocb, float* __restrict__ Sarr,
    float* __restrict__ sEnd){
  const int c = blockIdx.x, bh = blockIdx.y, b = bh>>3, h = bh&7, d = threadIdx.x;
  float s = 0.f, S = 1.f;
  const int t0 = c*CLEN;
  #pragma unroll 4
  for (int j=0;j<CLEN;++j){
    const int t = t0 + j;
    float a  = bf2f(proj[((size_t)(b*S_+t))*2048 + h*64 + d]);
    float sv = sdo[(b*S_+t)*8 + h];
    s = sv*s + (1.f-sv)*a;
    S *= sv;
    slocb[((size_t)bh*S_ + t)*64 + d] = f2bf(s);
    if (d==0) Sarr[bh*S_ + t] = S;
  }
  sEnd[((size_t)c*BH + bh)*64 + d] = s;
}

__global__ __launch_bounds__(64) void state_combine(
    const float* __restrict__ sEnd, const float* __restrict__ Sarr,
    float* __restrict__ sinit){
  const int bh = blockIdx.x, d = threadIdx.x;
  float acc = 0.f;
  for (int c=0;c<NCHUNK;++c){
    sinit[((size_t)c*BH + bh)*64 + d] = acc;
    const int te = c*CLEN + CLEN - 1;
    acc = Sarr[bh*S_ + te]*acc + sEnd[((size_t)c*BH + bh)*64 + d];
  }
}

// prev[t] = state_{t-1}, bf16
__global__ __launch_bounds__(256) void prev_mat(
    const unsigned short* __restrict__ slocb, const float* __restrict__ Sarr,
    const float* __restrict__ sinit, unsigned short* __restrict__ prevb){
  const size_t idx = (size_t)blockIdx.x*256 + threadIdx.x;
  const int d  = (int)(idx & 63);
  const size_t bt = idx >> 6;
  const int t  = (int)(bt & (S_-1));
  const int bh = (int)(bt >> 11);
  const int c = t >> 6, j = t & 63;
  float init = sinit[((size_t)c*BH + bh)*64 + d];
  float p;
  if (j==0) p = init;
  else {
    const size_t pt = (size_t)bh*S_ + (t-1);
    p = Sarr[pt]*init + bf2f(slocb[pt*64 + d]);
  }
  prevb[idx] = f2bf(p);
}

// ---------- pair chunk-local sums via MFMA ----------
__global__ __launch_bounds__(64) void pair_localm(
    const unsigned short* __restrict__ proj, const float* __restrict__ pdo,
    const unsigned short* __restrict__ prevb, float* __restrict__ pairbuf,
    float* __restrict__ Dprod){
  __shared__ __align__(16) unsigned short Bt[4096];
  __shared__ __align__(16) unsigned short Pt[4096];
  const int c=blockIdx.x, bh=blockIdx.y, b=bh>>3, h=bh&7, l=threadIdx.x;
  const int t = c*CLEN + l;
  float pd = pdo[(b*S_+t)*8 + h];
  float D = pd;
  #pragma unroll
  for (int m=1;m<64;m<<=1){ float o = __shfl_up(D, m); if (l>=m) D *= o; }
  const float Dend = __shfl(D, 63);
  const float cu = (Dend / D) * (1.f - pd);
  if (l==63) Dprod[c*BH+bh] = Dend;
  {
    const unsigned short* brow = proj  + ((size_t)(b*S_+t))*2048 + 512 + h*64;
    const unsigned short* prow = prevb + ((size_t)bh*S_ + t)*64;
    #pragma unroll
    for (int e8=0;e8<8;++e8){
      ushort4 u0 = *(const ushort4*)(brow + e8*8);
      ushort4 u1 = *(const ushort4*)(brow + e8*8 + 4);
      unsigned short vs[8] = {u0.x,u0.y,u0.z,u0.w,u1.x,u1.y,u1.z,u1.w};
      ushort4 p0 = *(const ushort4*)(prow + e8*8);
      ushort4 p1 = *(const ushort4*)(prow + e8*8 + 4);
      unsigned short ps[8] = {p0.x,p0.y,p0.z,p0.w,p1.x,p1.y,p1.z,p1.w};
      #pragma unroll
      for (int q=0;q<8;++q){
        const int r = e8*8+q;
        Bt[swz(r, l)] = f2bf(cu * bf2f(vs[q]));
        Pt[swz(r, l)] = ps[q];
      }
    }
  }
  __syncthreads();
  const int fr = l & 15, fq = l >> 4;
  floatx4 acc[4][4];
  #pragma unroll
  for (int i=0;i<4;++i)
    #pragma unroll
    for (int j=0;j<4;++j) acc[i][j] = (floatx4){0.f,0.f,0.f,0.f};
  #pragma unroll
  for (int kh=0;kh<2;++kh){
    bf16x8 af[4], bfr[4];
    #pragma unroll
    for (int i=0;i<4;++i) af[i]  = *(const bf16x8*)&Bt[swz(i*16+fr, kh*32+fq*8)];
    #pragma unroll
    for (int j=0;j<4;++j) bfr[j] = *(const bf16x8*)&Pt[swz(j*16+fr, kh*32+fq*8)];
    #pragma unroll
    for (int i=0;i<4;++i)
      #pragma unroll
      for (int j=0;j<4;++j)
        acc[i][j] = __builtin_amdgcn_mfma_f32_16x16x32_bf16(af[i], bfr[j], acc[i][j], 0, 0, 0);
  }
  float* outp = pairbuf + ((size_t)c*BH + bh)*4096;
  #pragma unroll
  for (int i=0;i<4;++i)
    #pragma unroll
    for (int j=0;j<4;++j)
      #pragma unroll
      for (int r=0;r<4;++r)
        outp[(i*16+fq*4+r)*64 + j*16+fr] = acc[i][j][r];
}

// in-place: pairbuf[c] (local sums) -> pair_init[c]
__global__ __launch_bounds__(256) void pair_combine(
    float* __restrict__ pairbuf, const float* __restrict__ Dprod){
  const int idx = blockIdx.x*256 + threadIdx.x;     // 262144
  const int de = idx & 4095, bh = idx >> 12;
  float acc = 0.f;
  for (int c=0;c<NCHUNK;++c){
    const size_t o = ((size_t)c*BH + bh)*4096 + de;
    float loc = pairbuf[o];
    pairbuf[o] = acc;
    acc = Dprod[c*BH + bh]*acc + loc;
  }
}

// ---------- pair final: masked linear attention via MFMA ----------
__global__ __launch_bounds__(64) void pair_finalm(
    const unsigned short* __restrict__ proj, const float* __restrict__ pdo,
    const unsigned short* __restrict__ prevb, const float* __restrict__ pinit,
    unsigned short* __restrict__ lcqr){
  __shared__ __align__(16) unsigned short Bt[4096];
  __shared__ __align__(16) unsigned short Tb[4096];
  __shared__ __align__(16) float Dtl[64];
  __shared__ __align__(16) float cudl[64];
  const int c=blockIdx.x, bh=blockIdx.y, b=bh>>3, h=bh&7, l=threadIdx.x;
  const int t0 = c*CLEN;
  const int trow = t0 + l;
  float pd = pdo[(b*S_+trow)*8 + h];
  float D = pd;
  #pragma unroll
  for (int m=1;m<64;m<<=1){ float o = __shfl_up(D, m); if (l>=m) D *= o; }
  Dtl[l]  = D;
  cudl[l] = (1.f - pd) / D;
  {
    const unsigned short* brow = proj + ((size_t)(b*S_+trow))*2048 + 512 + h*64;
    #pragma unroll
    for (int e8=0;e8<8;++e8){
      ushort4 u0 = *(const ushort4*)(brow + e8*8);
      ushort4 u1 = *(const ushort4*)(brow + e8*8 + 4);
      unsigned short vs[8] = {u0.x,u0.y,u0.z,u0.w,u1.x,u1.y,u1.z,u1.w};
      #pragma unroll
      for (int q=0;q<8;++q) Bt[swz(e8*8+q, l)] = vs[q];
    }
  }
  __syncthreads();
  const int fr = l & 15, fq = l >> 4;
  bf16x8 qf[4][2], pf[4][2];
  #pragma unroll
  for (int i=0;i<4;++i)
    #pragma unroll
    for (int kh=0;kh<2;++kh){
      qf[i][kh] = *(const bf16x8*)(proj  + ((size_t)(b*S_ + t0 + i*16 + fr))*2048 + 1024 + h*64 + kh*32 + fq*8);
      pf[i][kh] = *(const bf16x8*)(prevb + ((size_t)(bh*S_ + t0 + i*16 + fr))*64  + kh*32 + fq*8);
    }
  floatx4 sacc[4][4];
  #pragma unroll
  for (int i=0;i<4;++i)
    #pragma unroll
    for (int j=0;j<4;++j) sacc[i][j] = (floatx4){0.f,0.f,0.f,0.f};
  #pragma unroll
  for (int kh=0;kh<2;++kh)
    #pragma unroll
    for (int i=0;i<4;++i)
      #pragma unroll
      for (int j=0;j<4;++j)
        sacc[i][j] = __builtin_amdgcn_mfma_f32_16x16x32_bf16(qf[i][kh], pf[j][kh], sacc[i][j], 0, 0, 0);
  float mycud[4];
  #pragma unroll
  for (int j=0;j<4;++j) mycud[j] = cudl[j*16+fr];
  #pragma unroll
  for (int i=0;i<4;++i){
    floatx4 dtv = *(const floatx4*)&Dtl[i*16+fq*4];
    #pragma unroll
    for (int j=0;j<4;++j){
      const int uu = j*16+fr;
      #pragma unroll
      for (int r=0;r<4;++r){
        const int tt = i*16+fq*4+r;
        float v = (uu<=tt) ? (sacc[i][j][r]*dtv[r])*mycud[j] : 0.f;
        Tb[swz(tt, uu)] = f2bf(v);
      }
    }
  }
  __syncthreads();
  floatx4 acc[4][4];
  #pragma unroll
  for (int i=0;i<4;++i)
    #pragma unroll
    for (int j=0;j<4;++j) acc[i][j] = (floatx4){0.f,0.f,0.f,0.f};
  #pragma unroll
  for (int kh=0;kh<2;++kh){
    bf16x8 af[4], bfr[4];
    #pragma unroll
    for (int i=0;i<4;++i) af[i]  = *(const bf16x8*)&Tb[swz(i*16+fr, kh*32+fq*8)];
    #pragma unroll
    for (int j=0;j<4;++j) bfr[j] = *(const bf16x8*)&Bt[swz(j*16+fr, kh*32+fq*8)];
    #pragma unroll
    for (int i=0;i<4;++i)
      #pragma unroll
      for (int j=0;j<4;++j)
        acc[i][j] = __builtin_amdgcn_mfma_f32_16x16x32_bf16(af[i], bfr[j], acc[i][j], 0, 0, 0);
  }
  {
    const float* ibase = pinit + ((size_t)c*BH + bh)*4096;
    #pragma unroll
    for (int kh=0;kh<2;++kh){
      bf16x8 qs[4], inf[4];
      #pragma unroll
      for (int i=0;i<4;++i){
        const float sc = Dtl[i*16+fr];
        #pragma unroll
        for (int e=0;e<8;++e) qs[i][e] = (__bf16)(sc * (float)qf[i][kh][e]);
      }
      #pragma unroll
      for (int j=0;j<4;++j){
        const float* ip = ibase + (j*16+fr)*64 + kh*32 + fq*8;
        float4 f0 = *(const float4*)ip;
        float4 f1 = *(const float4*)(ip+4);
        inf[j][0]=(__bf16)f0.x; inf[j][1]=(__bf16)f0.y; inf[j][2]=(__bf16)f0.z; inf[j][3]=(__bf16)f0.w;
        inf[j][4]=(__bf16)f1.x; inf[j][5]=(__bf16)f1.y; inf[j][6]=(__bf16)f1.z; inf[j][7]=(__bf16)f1.w;
      }
      #pragma unroll
      for (int i=0;i<4;++i)
        #pragma unroll
        for (int j=0;j<4;++j)
          acc[i][j] = __builtin_amdgcn_mfma_f32_16x16x32_bf16(qs[i], inf[j], acc[i][j], 0, 0, 0);
    }
  }
  __syncthreads();
  #pragma unroll
  for (int i=0;i<4;++i)
    #pragma unroll
    for (int j=0;j<4;++j)
      #pragma unroll
      for (int r=0;r<4;++r)
        Tb[swz(i*16+fq*4+r, j*16+fr)] = f2bf(acc[i][j][r]);
  __syncthreads();
  {
    const unsigned short* qrow = proj + ((size_t)(b*S_+trow))*2048 + 1536 + h*64;
    unsigned short* orow = lcqr + ((size_t)(b*S_+trow))*512 + h*64;
    #pragma unroll
    for (int e8=0;e8<8;++e8){
      bf16x8 lcv = *(const bf16x8*)&Tb[swz(l, e8*8)];
      ushort4 q0 = *(const ushort4*)(qrow + e8*8);
      ushort4 q1 = *(const ushort4*)(qrow + e8*8 + 4);
      unsigned short qv[8] = {q0.x,q0.y,q0.z,q0.w,q1.x,q1.y,q1.z,q1.w};
      ushort4 o0, o1;
      o0.x = f2bf((float)lcv[0]*bf2f(qv[0]));
      o0.y = f2bf((float)lcv[1]*bf2f(qv[1]));
      o0.z = f2bf((float)lcv[2]*bf2f(qv[2]));
      o0.w = f2bf((float)lcv[3]*bf2f(qv[3]));
      o1.x = f2bf((float)lcv[4]*bf2f(qv[4]));
      o1.y = f2bf((float)lcv[5]*bf2f(qv[5]));
      o1.z = f2bf((float)lcv[6]*bf2f(qv[6]));
      o1.w = f2bf((float)lcv[7]*bf2f(qv[7]));
      *(ushort4*)(orow + e8*8)     = o0;
      *(ushort4*)(orow + e8*8 + 4) = o1;
    }
  }
}

// ---------- launch ----------
extern "C" void kernel_launch(void* const* d_in, const int* in_sizes, int n_in,
                              void* d_out, int out_size, void* d_ws, size_t ws_size,
                              hipStream_t stream){
  (void)in_sizes; (void)n_in; (void)out_size; (void)ws_size;
  const float* x    = (const float*)d_in[0];
  const float* ng   = (const float*)d_in[1];
  const float* nb   = (const float*)d_in[2];
  const float* fng  = (const float*)d_in[3];
  const float* fnb  = (const float*)d_in[4];
  const float* Wa   = (const float*)d_in[5];
  const float* Wb   = (const float*)d_in[6];
  const float* Wql  = (const float*)d_in[7];
  const float* Wqr  = (const float*)d_in[8];
  const float* Wsd  = (const float*)d_in[9];
  const float* bsd  = (const float*)d_in[10];
  const float* Wpd  = (const float*)d_in[11];
  const float* bpd  = (const float*)d_in[12];
  const float* Wout = (const float*)d_in[13];
  const float* W1   = (const float*)d_in[14];
  const float* b1   = (const float*)d_in[15];
  const float* W2   = (const float*)d_in[16];
  const float* b2   = (const float*)d_in[17];
  float* out = (float*)d_out;
  char* ws = (char*)d_ws;

  size_t off = 0;
  auto alloc = [&](size_t bytes)->char*{ char* p = ws + off; off += (bytes + 255) & ~(size_t)255; return p; };
  char* RA = alloc((size_t)ROWS*DM_*2);      // nbf -> lcqr -> nr
  char* RB = alloc((size_t)ROWS*2048*2);     // proj -> hbuf
  char* RD = alloc((size_t)BH*S_*64*4);      // slocb(bf16,front) -> pairb(f32,full)
  char* RE = alloc((size_t)BH*S_*64*4);      // prevb(bf16) -> rbufb(bf16)
  float* sdo   = (float*)alloc((size_t)ROWS*8*4);
  float* pdo   = (float*)alloc((size_t)ROWS*8*4);
  float* Sarr  = (float*)alloc((size_t)BH*S_*4);
  float* sinit = (float*)alloc((size_t)NCHUNK*BH*64*4);
  float* sEnd  = (float*)alloc((size_t)NCHUNK*BH*64*4);
  float* dprod = (float*)alloc((size_t)NCHUNK*BH*4);
  unsigned short* wcat  = (unsigned short*)alloc((size_t)2048*512*2);
  unsigned short* woutb = (unsigned short*)alloc((size_t)512*512*2);
  unsigned short* w1b   = (unsigned short*)alloc((size_t)2048*512*2);
  unsigned short* w2b   = (unsigned short*)alloc((size_t)512*2048*2);

  unsigned short* nbf   = (unsigned short*)RA;
  unsigned short* lcqr  = (unsigned short*)RA;
  unsigned short* nr    = (unsigned short*)RA;
  unsigned short* proj  = (unsigned short*)RB;
  unsigned short* hbuf  = (unsigned short*)RB;
  unsigned short* slocb = (unsigned short*)RD;
  float* pairb = (float*)RD;
  unsigned short* prevb = (unsigned short*)RE;
  unsigned short* rbufb = (unsigned short*)RE;

  cvt_weights<<<dim3(3328), dim3(256), 0, stream>>>(Wa,Wb,Wql,Wqr,Wout,W1,W2, wcat,woutb,w1b,w2b);
  ln_gates<<<dim3(ROWS), dim3(64), 0, stream>>>(x, ng, nb, Wsd, bsd, Wpd, bpd, nbf, sdo, pdo);
  gemm256<0><<<dim3(64,8), dim3(512), 0, stream>>>(nbf, wcat, nullptr, proj, 2048, 512);
  state_local<<<dim3(NCHUNK,BH), dim3(64), 0, stream>>>(proj, sdo, slocb, Sarr, sEnd);
  state_combine<<<dim3(BH), dim3(64), 0, stream>>>(sEnd, Sarr, sinit);
  prev_mat<<<dim3(32768), dim3(256), 0, stream>>>(slocb, Sarr, sinit, prevb);
  pair_localm<<<dim3(NCHUNK,BH), dim3(64), 0, stream>>>(proj, pdo, prevb, pairb, dprod);
  pair_combine<<<dim3(1024), dim3(256), 0, stream>>>(pairb, dprod);
  pair_finalm<<<dim3(NCHUNK,BH), dim3(64), 0, stream>>>(proj, pdo, prevb, pairb, lcqr);
  gemm128<1><<<dim3(128,4), dim3(256), 0, stream>>>(lcqr, woutb, nullptr, x, nullptr, nullptr, rbufb, 512, 512);
  ln_plain<<<dim3(ROWS), dim3(64), 0, stream>>>(rbufb, fng, fnb, nr);
  gemm256<2><<<dim3(64,8), dim3(512), 0, stream>>>(nr, w1b, b1, hbuf, 2048, 512);
  gemm128<3><<<dim3(128,4), dim3(256), 0, stream>>>(hbuf, w2b, b2, nullptr, rbufb, out, nullptr, 512, 2048);
}

// Round 6
// 433.888 us; speedup vs baseline: 1.0355x; 1.0355x over previous
//
#include <hip/hip_runtime.h>
#include <cstdint>
#include <cstddef>

// Problem constants
#define B_    8
#define S_    2048
#define DM_   512
#define H_    8
#define SD_   64
#define HID_  2048
#define ROWS  (B_*S_)      // 16384
#define BH    (B_*H_)      // 64
#define NCHUNK 32
#define CLEN   64
#define EPS_  1e-5f

typedef __bf16 bf16x8 __attribute__((ext_vector_type(8)));
typedef float  floatx4 __attribute__((ext_vector_type(4)));

// ---------- small helpers ----------
static __device__ __forceinline__ float bf2f(unsigned short h){
  union { unsigned int u; float f; } v; v.u = ((unsigned int)h) << 16; return v.f;
}
static __device__ __forceinline__ unsigned short f2bf(float f){
  union { float f; unsigned int u; } v; v.f = f;
  unsigned int r = v.u + 0x7fffu + ((v.u >> 16) & 1u);
  return (unsigned short)(r >> 16);
}
static __device__ __forceinline__ float fast_tanh(float x){
  float ax = fabsf(x);
  float e  = __expf(2.f*ax);
  float t  = 1.f - 2.f/(e+1.f);
  return copysignf(t, x);
}
static __device__ __forceinline__ float sigmoidf_(float z){
  return 1.f/(1.f + expf(-z));
}
static __device__ __forceinline__ float gelu_exact(float x){
  return 0.5f*x*(1.f + erff(x*0.70710678118654752440f));
}
static __device__ __forceinline__ void gld_lds16(const unsigned short* g, unsigned short* lds){
  __builtin_amdgcn_global_load_lds(
      (const __attribute__((address_space(1))) void*)g,
      (__attribute__((address_space(3))) void*)lds,
      16, 0, 0);
}
// XOR swizzle for 64-half (128B) rows: 16B chunk kc of row r stored at chunk kc^(r&7)
static __device__ __forceinline__ int swz(int row, int col){
  return row*64 + (((col>>3) ^ (row&7))<<3) + (col&7);
}

// ---------- weight fp32 -> bf16 conversion ----------
__global__ __launch_bounds__(256) void cvt_weights(
    const float* __restrict__ wa, const float* __restrict__ wb,
    const float* __restrict__ wql, const float* __restrict__ wqr,
    const float* __restrict__ wout, const float* __restrict__ w1,
    const float* __restrict__ w2,
    unsigned short* __restrict__ wcat, unsigned short* __restrict__ woutb,
    unsigned short* __restrict__ w1b, unsigned short* __restrict__ w2b){
  int i = blockIdx.x*256 + threadIdx.x;   // float4 units, total 851968
  const float* s; unsigned short* d; int base;
  if      (i <  65536){ s=wa;   d=wcat;          base=i; }
  else if (i < 131072){ s=wb;   d=wcat+262144;   base=i-65536; }
  else if (i < 196608){ s=wql;  d=wcat+524288;   base=i-131072; }
  else if (i < 262144){ s=wqr;  d=wcat+786432;   base=i-196608; }
  else if (i < 327680){ s=wout; d=woutb;         base=i-262144; }
  else if (i < 589824){ s=w1;   d=w1b;           base=i-327680; }
  else                { s=w2;   d=w2b;           base=i-589824; }
  float4 v = ((const float4*)s)[base];
  ushort4 o; o.x=f2bf(v.x); o.y=f2bf(v.y); o.z=f2bf(v.z); o.w=f2bf(v.w);
  ((ushort4*)d)[base] = o;
}

// ---------- LN1 + gate heads ----------
__global__ __launch_bounds__(64) void ln_gates(
    const float* __restrict__ x, const float* __restrict__ gam, const float* __restrict__ bet,
    const float* __restrict__ Wsd, const float* __restrict__ bsd,
    const float* __restrict__ Wpd, const float* __restrict__ bpd,
    unsigned short* __restrict__ nbf, float* __restrict__ sdo, float* __restrict__ pdo){
  const int row = blockIdx.x, l = threadIdx.x;
  const float* xr = x + (size_t)row*DM_;
  float4 v0 = ((const float4*)xr)[l*2];
  float4 v1 = ((const float4*)xr)[l*2+1];
  float v[8] = {v0.x,v0.y,v0.z,v0.w,v1.x,v1.y,v1.z,v1.w};
  float s = 0.f;
  #pragma unroll
  for (int i=0;i<8;++i) s += v[i];
  #pragma unroll
  for (int m=1;m<64;m<<=1) s += __shfl_xor(s, m);
  const float mean = s * (1.f/512.f);
  float q = 0.f;
  #pragma unroll
  for (int i=0;i<8;++i){ float d = v[i]-mean; q += d*d; }
  #pragma unroll
  for (int m=1;m<64;m<<=1) q += __shfl_xor(q, m);
  const float rstd = rsqrtf(q*(1.f/512.f) + EPS_);
  float4 g0 = ((const float4*)gam)[l*2], g1 = ((const float4*)gam)[l*2+1];
  float4 b0 = ((const float4*)bet)[l*2], b1 = ((const float4*)bet)[l*2+1];
  float gg[8] = {g0.x,g0.y,g0.z,g0.w,g1.x,g1.y,g1.z,g1.w};
  float bb[8] = {b0.x,b0.y,b0.z,b0.w,b1.x,b1.y,b1.z,b1.w};
  float n[8];
  #pragma unroll
  for (int i=0;i<8;++i) n[i] = (v[i]-mean)*rstd*gg[i] + bb[i];
  ushort4 o0, o1;
  o0.x=f2bf(n[0]); o0.y=f2bf(n[1]); o0.z=f2bf(n[2]); o0.w=f2bf(n[3]);
  o1.x=f2bf(n[4]); o1.y=f2bf(n[5]); o1.z=f2bf(n[6]); o1.w=f2bf(n[7]);
  ((ushort4*)(nbf + (size_t)row*DM_))[l*2]   = o0;
  ((ushort4*)(nbf + (size_t)row*DM_))[l*2+1] = o1;
  float acc[16];
  #pragma unroll
  for (int hh=0; hh<8; ++hh){
    const float4* ws = (const float4*)(Wsd + hh*DM_) + l*2;
    const float4* wp = (const float4*)(Wpd + hh*DM_) + l*2;
    float4 a0=ws[0], a1=ws[1], p0=wp[0], p1=wp[1];
    acc[hh]   = n[0]*a0.x+n[1]*a0.y+n[2]*a0.z+n[3]*a0.w+n[4]*a1.x+n[5]*a1.y+n[6]*a1.z+n[7]*a1.w;
    acc[8+hh] = n[0]*p0.x+n[1]*p0.y+n[2]*p0.z+n[3]*p0.w+n[4]*p1.x+n[5]*p1.y+n[6]*p1.z+n[7]*p1.w;
  }
  #pragma unroll
  for (int k=0;k<16;++k){
    float a = acc[k];
    #pragma unroll
    for (int m=1;m<64;m<<=1) a += __shfl_xor(a, m);
    acc[k] = a;
  }
  if (l==0){
    #pragma unroll
    for (int hh=0; hh<8; ++hh){
      sdo[row*8+hh] = sigmoidf_(acc[hh]   + bsd[hh]);
      pdo[row*8+hh] = sigmoidf_(acc[8+hh] + bpd[hh]);
    }
  }
}

// ---------- plain LN (FFN), bf16 input ----------
__global__ __launch_bounds__(64) void ln_plain(
    const unsigned short* __restrict__ xb, const float* __restrict__ gam, const float* __restrict__ bet,
    unsigned short* __restrict__ ob){
  const int row = blockIdx.x, l = threadIdx.x;
  const unsigned short* xr = xb + (size_t)row*DM_ + l*8;
  ushort4 u0 = *(const ushort4*)xr;
  ushort4 u1 = *(const ushort4*)(xr+4);
  float v[8] = {bf2f(u0.x),bf2f(u0.y),bf2f(u0.z),bf2f(u0.w),
                bf2f(u1.x),bf2f(u1.y),bf2f(u1.z),bf2f(u1.w)};
  float s = 0.f;
  #pragma unroll
  for (int i=0;i<8;++i) s += v[i];
  #pragma unroll
  for (int m=1;m<64;m<<=1) s += __shfl_xor(s, m);
  const float mean = s * (1.f/512.f);
  float q = 0.f;
  #pragma unroll
  for (int i=0;i<8;++i){ float d = v[i]-mean; q += d*d; }
  #pragma unroll
  for (int m=1;m<64;m<<=1) q += __shfl_xor(q, m);
  const float rstd = rsqrtf(q*(1.f/512.f) + EPS_);
  float4 g0 = ((const float4*)gam)[l*2], g1 = ((const float4*)gam)[l*2+1];
  float4 b0 = ((const float4*)bet)[l*2], b1 = ((const float4*)bet)[l*2+1];
  float gg[8] = {g0.x,g0.y,g0.z,g0.w,g1.x,g1.y,g1.z,g1.w};
  float bb[8] = {b0.x,b0.y,b0.z,b0.w,b1.x,b1.y,b1.z,b1.w};
  ushort4 o0, o1;
  o0.x=f2bf((v[0]-mean)*rstd*gg[0]+bb[0]); o0.y=f2bf((v[1]-mean)*rstd*gg[1]+bb[1]);
  o0.z=f2bf((v[2]-mean)*rstd*gg[2]+bb[2]); o0.w=f2bf((v[3]-mean)*rstd*gg[3]+bb[3]);
  o1.x=f2bf((v[4]-mean)*rstd*gg[4]+bb[4]); o1.y=f2bf((v[5]-mean)*rstd*gg[5]+bb[5]);
  o1.z=f2bf((v[6]-mean)*rstd*gg[6]+bb[6]); o1.w=f2bf((v[7]-mean)*rstd*gg[7]+bb[7]);
  ((ushort4*)(ob + (size_t)row*DM_))[l*2]   = o0;
  ((ushort4*)(ob + (size_t)row*DM_))[l*2+1] = o1;
}

// ---------- 128x128-tile GEMM, BK=64, single-buffered (measured-best baseline) ----------
// MODE 0: tanh -> bf16; 1: +resid(f32) -> bf16; 2: +bias,gelu -> bf16; 3: +bias+resid(bf16) -> f32
template<int MODE>
__global__ __launch_bounds__(256) void gemm128(
    const unsigned short* __restrict__ A, const unsigned short* __restrict__ W,
    const float* __restrict__ bias, const float* __restrict__ residf,
    const unsigned short* __restrict__ residb,
    float* __restrict__ outf, unsigned short* __restrict__ outb,
    int N, int K){
  __shared__ __align__(16) unsigned short As[128*64];
  __shared__ __align__(16) unsigned short Ws[128*64];
  const int tid  = threadIdx.x;
  const int w    = tid >> 6;
  const int lane = tid & 63;
  const int mblk = blockIdx.x, nblk = blockIdx.y;
  const int mrow = (w >> 1) * 64;
  const int ncol = (w & 1) * 64;
  const int fr = lane & 15, fq = lane >> 4;

  int srow[4], scol[4];
  #pragma unroll
  for (int q=0;q<4;++q){
    const int p = q*256 + w*64 + lane;
    srow[q] = p >> 3;
    scol[q] = ((p & 7) ^ (srow[q] & 7)) * 8;
  }

  floatx4 acc[4][4];
  #pragma unroll
  for (int i=0;i<4;++i)
    #pragma unroll
    for (int j=0;j<4;++j)
      acc[i][j] = (floatx4){0.f,0.f,0.f,0.f};

  for (int k0=0; k0<K; k0+=64){
    #pragma unroll
    for (int q=0;q<4;++q){
      gld_lds16(A + (size_t)(mblk*128 + srow[q])*K + k0 + scol[q], As + (q*256 + w*64)*8);
      gld_lds16(W + (size_t)(nblk*128 + srow[q])*K + k0 + scol[q], Ws + (q*256 + w*64)*8);
    }
    __syncthreads();
    #pragma unroll
    for (int kh=0;kh<2;++kh){
      bf16x8 af[4], bf[4];
      #pragma unroll
      for (int i=0;i<4;++i) af[i] = *(const bf16x8*)&As[swz(mrow + i*16 + fr, kh*32 + fq*8)];
      #pragma unroll
      for (int j=0;j<4;++j) bf[j] = *(const bf16x8*)&Ws[swz(ncol + j*16 + fr, kh*32 + fq*8)];
      #pragma unroll
      for (int i=0;i<4;++i)
        #pragma unroll
        for (int j=0;j<4;++j)
          acc[i][j] = __builtin_amdgcn_mfma_f32_16x16x32_bf16(af[i], bf[j], acc[i][j], 0, 0, 0);
    }
    __syncthreads();
  }

  #pragma unroll
  for (int i=0;i<4;++i){
    const int grow_base = mblk*128 + mrow + i*16 + fq*4;
    #pragma unroll
    for (int j=0;j<4;++j){
      const int gcol = nblk*128 + ncol + j*16 + fr;
      float bias_v = 0.f;
      if (MODE==2 || MODE==3) bias_v = bias[gcol];
      #pragma unroll
      for (int r=0;r<4;++r){
        const size_t o = (size_t)(grow_base + r)*N + gcol;
        float v = acc[i][j][r];
        if      (MODE==0) outb[o] = f2bf(fast_tanh(v));
        else if (MODE==1) outb[o] = f2bf(residf[o] + v);
        else if (MODE==2) outb[o] = f2bf(gelu_exact(v + bias_v));
        else              outf[o] = bf2f(residb[o]) + v + bias_v;
      }
    }
  }
}

// ---------- 128x128-tile GEMM, BK=64, double-buffered LDS (experimental; A/B vs gemm128) ----------
// One barrier per K-iter; DMA for tile k+1 issued right after the barrier so the
// next barrier's vmcnt(0) drain hits a load that has the whole MFMA block in flight.
template<int MODE>
__global__ __launch_bounds__(256) void gemm128db(
    const unsigned short* __restrict__ A, const unsigned short* __restrict__ W,
    unsigned short* __restrict__ outb, int N, int K){
  __shared__ __align__(16) unsigned short As[2][128*64];   // 2 x 16 KB
  __shared__ __align__(16) unsigned short Ws[2][128*64];   // 2 x 16 KB
  const int tid  = threadIdx.x;
  const int w    = tid >> 6;
  const int lane = tid & 63;
  const int mblk = blockIdx.x, nblk = blockIdx.y;
  const int mrow = (w >> 1) * 64;
  const int ncol = (w & 1) * 64;
  const int fr = lane & 15, fq = lane >> 4;

  int srow[4], scol[4];
  #pragma unroll
  for (int q=0;q<4;++q){
    const int p = q*256 + w*64 + lane;
    srow[q] = p >> 3;
    scol[q] = ((p & 7) ^ (srow[q] & 7)) * 8;
  }

  floatx4 acc[4][4];
  #pragma unroll
  for (int i=0;i<4;++i)
    #pragma unroll
    for (int j=0;j<4;++j)
      acc[i][j] = (floatx4){0.f,0.f,0.f,0.f};

  // prologue: DMA tile 0 -> buffer 0
  #pragma unroll
  for (int q=0;q<4;++q){
    gld_lds16(A + (size_t)(mblk*128 + srow[q])*K + scol[q], As[0] + (q*256 + w*64)*8);
    gld_lds16(W + (size_t)(nblk*128 + srow[q])*K + scol[q], Ws[0] + (q*256 + w*64)*8);
  }

  const int nk = K >> 6;
  for (int it=0; it<nk; ++it){
    const int cur = it & 1;
    __syncthreads();                 // drains DMA for buf(cur); also fences reads of buf(1-cur)
    if (it+1 < nk){
      const int k1 = (it+1) << 6;
      #pragma unroll
      for (int q=0;q<4;++q){
        gld_lds16(A + (size_t)(mblk*128 + srow[q])*K + k1 + scol[q], As[1-cur] + (q*256 + w*64)*8);
        gld_lds16(W + (size_t)(nblk*128 + srow[q])*K + k1 + scol[q], Ws[1-cur] + (q*256 + w*64)*8);
      }
    }
    #pragma unroll
    for (int kh=0;kh<2;++kh){
      bf16x8 af[4], bf[4];
      #pragma unroll
      for (int i=0;i<4;++i) af[i] = *(const bf16x8*)&As[cur][swz(mrow + i*16 + fr, kh*32 + fq*8)];
      #pragma unroll
      for (int j=0;j<4;++j) bf[j] = *(const bf16x8*)&Ws[cur][swz(ncol + j*16 + fr, kh*32 + fq*8)];
      #pragma unroll
      for (int i=0;i<4;++i)
        #pragma unroll
        for (int j=0;j<4;++j)
          acc[i][j] = __builtin_amdgcn_mfma_f32_16x16x32_bf16(af[i], bf[j], acc[i][j], 0, 0, 0);
    }
  }

  #pragma unroll
  for (int i=0;i<4;++i){
    const int grow_base = mblk*128 + mrow + i*16 + fq*4;
    #pragma unroll
    for (int j=0;j<4;++j){
      const int gcol = nblk*128 + ncol + j*16 + fr;
      #pragma unroll
      for (int r=0;r<4;++r){
        const size_t o = (size_t)(grow_base + r)*N + gcol;
        outb[o] = f2bf(fast_tanh(acc[i][j][r]));   // MODE 0 only
      }
    }
  }
}

// ---------- state scan, chunk-local (bf16 sloc + f32 chunk ends) ----------
__global__ __launch_bounds__(64) void state_local(
    const unsigned short* __restrict__ proj, const float* __restrict__ sdo,
    unsigned short* __restrict__ slocb, float* __restrict__ Sarr,
    float* __restrict__ sEnd){
  const int c = blockIdx.x, bh = blockIdx.y, b = bh>>3, h = bh&7, d = threadIdx.x;
  float s = 0.f, S = 1.f;
  const int t0 = c*CLEN;
  #pragma unroll 4
  for (int j=0;j<CLEN;++j){
    const int t = t0 + j;
    float a  = bf2f(proj[((size_t)(b*S_+t))*2048 + h*64 + d]);
    float sv = sdo[(b*S_+t)*8 + h];
    s = sv*s + (1.f-sv)*a;
    S *= sv;
    slocb[((size_t)bh*S_ + t)*64 + d] = f2bf(s);
    if (d==0) Sarr[bh*S_ + t] = S;
  }
  sEnd[((size_t)c*BH + bh)*64 + d] = s;
}

__global__ __launch_bounds__(64) void state_combine(
    const float* __restrict__ sEnd, const float* __restrict__ Sarr,
    float* __restrict__ sinit){
  const int bh = blockIdx.x, d = threadIdx.x;
  float acc = 0.f;
  for (int c=0;c<NCHUNK;++c){
    sinit[((size_t)c*BH + bh)*64 + d] = acc;
    const int te = c*CLEN + CLEN - 1;
    acc = Sarr[bh*S_ + te]*acc + sEnd[((size_t)c*BH + bh)*64 + d];
  }
}

// prev[t] = state_{t-1}, bf16
__global__ __launch_bounds__(256) void prev_mat(
    const unsigned short* __restrict__ slocb, const float* __restrict__ Sarr,
    const float* __restrict__ sinit, unsigned short* __restrict__ prevb){
  const size_t idx = (size_t)blockIdx.x*256 + threadIdx.x;
  const int d  = (int)(idx & 63);
  const size_t bt = idx >> 6;
  const int t  = (int)(bt & (S_-1));
  const int bh = (int)(bt >> 11);
  const int c = t >> 6, j = t & 63;
  float init = sinit[((size_t)c*BH + bh)*64 + d];
  float p;
  if (j==0) p = init;
  else {
    const size_t pt = (size_t)bh*S_ + (t-1);
    p = Sarr[pt]*init + bf2f(slocb[pt*64 + d]);
  }
  prevb[idx] = f2bf(p);
}

// ---------- pair chunk-local sums via MFMA ----------
__global__ __launch_bounds__(64) void pair_localm(
    const unsigned short* __restrict__ proj, const float* __restrict__ pdo,
    const unsigned short* __restrict__ prevb, float* __restrict__ pairbuf,
    float* __restrict__ Dprod){
  __shared__ __align__(16) unsigned short Bt[4096];
  __shared__ __align__(16) unsigned short Pt[4096];
  const int c=blockIdx.x, bh=blockIdx.y, b=bh>>3, h=bh&7, l=threadIdx.x;
  const int t = c*CLEN + l;
  float pd = pdo[(b*S_+t)*8 + h];
  float D = pd;
  #pragma unroll
  for (int m=1;m<64;m<<=1){ float o = __shfl_up(D, m); if (l>=m) D *= o; }
  const float Dend = __shfl(D, 63);
  const float cu = (Dend / D) * (1.f - pd);
  if (l==63) Dprod[c*BH+bh] = Dend;
  {
    const unsigned short* brow = proj  + ((size_t)(b*S_+t))*2048 + 512 + h*64;
    const unsigned short* prow = prevb + ((size_t)bh*S_ + t)*64;
    #pragma unroll
    for (int e8=0;e8<8;++e8){
      ushort4 u0 = *(const ushort4*)(brow + e8*8);
      ushort4 u1 = *(const ushort4*)(brow + e8*8 + 4);
      unsigned short vs[8] = {u0.x,u0.y,u0.z,u0.w,u1.x,u1.y,u1.z,u1.w};
      ushort4 p0 = *(const ushort4*)(prow + e8*8);
      ushort4 p1 = *(const ushort4*)(prow + e8*8 + 4);
      unsigned short ps[8] = {p0.x,p0.y,p0.z,p0.w,p1.x,p1.y,p1.z,p1.w};
      #pragma unroll
      for (int q=0;q<8;++q){
        const int r = e8*8+q;
        Bt[swz(r, l)] = f2bf(cu * bf2f(vs[q]));
        Pt[swz(r, l)] = ps[q];
      }
    }
  }
  __syncthreads();
  const int fr = l & 15, fq = l >> 4;
  floatx4 acc[4][4];
  #pragma unroll
  for (int i=0;i<4;++i)
    #pragma unroll
    for (int j=0;j<4;++j) acc[i][j] = (floatx4){0.f,0.f,0.f,0.f};
  #pragma unroll
  for (int kh=0;kh<2;++kh){
    bf16x8 af[4], bfr[4];
    #pragma unroll
    for (int i=0;i<4;++i) af[i]  = *(const bf16x8*)&Bt[swz(i*16+fr, kh*32+fq*8)];
    #pragma unroll
    for (int j=0;j<4;++j) bfr[j] = *(const bf16x8*)&Pt[swz(j*16+fr, kh*32+fq*8)];
    #pragma unroll
    for (int i=0;i<4;++i)
      #pragma unroll
      for (int j=0;j<4;++j)
        acc[i][j] = __builtin_amdgcn_mfma_f32_16x16x32_bf16(af[i], bfr[j], acc[i][j], 0, 0, 0);
  }
  float* outp = pairbuf + ((size_t)c*BH + bh)*4096;
  #pragma unroll
  for (int i=0;i<4;++i)
    #pragma unroll
    for (int j=0;j<4;++j)
      #pragma unroll
      for (int r=0;r<4;++r)
        outp[(i*16+fq*4+r)*64 + j*16+fr] = acc[i][j][r];
}

// in-place: pairbuf[c] (local sums) -> pair_init[c]
__global__ __launch_bounds__(256) void pair_combine(
    float* __restrict__ pairbuf, const float* __restrict__ Dprod){
  const int idx = blockIdx.x*256 + threadIdx.x;     // 262144
  const int de = idx & 4095, bh = idx >> 12;
  float acc = 0.f;
  for (int c=0;c<NCHUNK;++c){
    const size_t o = ((size_t)c*BH + bh)*4096 + de;
    float loc = pairbuf[o];
    pairbuf[o] = acc;
    acc = Dprod[c*BH + bh]*acc + loc;
  }
}

// ---------- pair final: masked linear attention via MFMA ----------
__global__ __launch_bounds__(64) void pair_finalm(
    const unsigned short* __restrict__ proj, const float* __restrict__ pdo,
    const unsigned short* __restrict__ prevb, const float* __restrict__ pinit,
    unsigned short* __restrict__ lcqr){
  __shared__ __align__(16) unsigned short Bt[4096];
  __shared__ __align__(16) unsigned short Tb[4096];
  __shared__ __align__(16) float Dtl[64];
  __shared__ __align__(16) float cudl[64];
  const int c=blockIdx.x, bh=blockIdx.y, b=bh>>3, h=bh&7, l=threadIdx.x;
  const int t0 = c*CLEN;
  const int trow = t0 + l;
  float pd = pdo[(b*S_+trow)*8 + h];
  float D = pd;
  #pragma unroll
  for (int m=1;m<64;m<<=1){ float o = __shfl_up(D, m); if (l>=m) D *= o; }
  Dtl[l]  = D;
  cudl[l] = (1.f - pd) / D;
  {
    const unsigned short* brow = proj + ((size_t)(b*S_+trow))*2048 + 512 + h*64;
    #pragma unroll
    for (int e8=0;e8<8;++e8){
      ushort4 u0 = *(const ushort4*)(brow + e8*8);
      ushort4 u1 = *(const ushort4*)(brow + e8*8 + 4);
      unsigned short vs[8] = {u0.x,u0.y,u0.z,u0.w,u1.x,u1.y,u1.z,u1.w};
      #pragma unroll
      for (int q=0;q<8;++q) Bt[swz(e8*8+q, l)] = vs[q];
    }
  }
  __syncthreads();
  const int fr = l & 15, fq = l >> 4;
  bf16x8 qf[4][2], pf[4][2];
  #pragma unroll
  for (int i=0;i<4;++i)
    #pragma unroll
    for (int kh=0;kh<2;++kh){
      qf[i][kh] = *(const bf16x8*)(proj  + ((size_t)(b*S_ + t0 + i*16 + fr))*2048 + 1024 + h*64 + kh*32 + fq*8);
      pf[i][kh] = *(const bf16x8*)(prevb + ((size_t)(bh*S_ + t0 + i*16 + fr))*64  + kh*32 + fq*8);
    }
  floatx4 sacc[4][4];
  #pragma unroll
  for (int i=0;i<4;++i)
    #pragma unroll
    for (int j=0;j<4;++j) sacc[i][j] = (floatx4){0.f,0.f,0.f,0.f};
  #pragma unroll
  for (int kh=0;kh<2;++kh)
    #pragma unroll
    for (int i=0;i<4;++i)
      #pragma unroll
      for (int j=0;j<4;++j)
        sacc[i][j] = __builtin_amdgcn_mfma_f32_16x16x32_bf16(qf[i][kh], pf[j][kh], sacc[i][j], 0, 0, 0);
  float mycud[4];
  #pragma unroll
  for (int j=0;j<4;++j) mycud[j] = cudl[j*16+fr];
  #pragma unroll
  for (int i=0;i<4;++i){
    floatx4 dtv = *(const floatx4*)&Dtl[i*16+fq*4];
    #pragma unroll
    for (int j=0;j<4;++j){
      const int uu = j*16+fr;
      #pragma unroll
      for (int r=0;r<4;++r){
        const int tt = i*16+fq*4+r;
        float v = (uu<=tt) ? (sacc[i][j][r]*dtv[r])*mycud[j] : 0.f;
        Tb[swz(tt, uu)] = f2bf(v);
      }
    }
  }
  __syncthreads();
  floatx4 acc[4][4];
  #pragma unroll
  for (int i=0;i<4;++i)
    #pragma unroll
    for (int j=0;j<4;++j) acc[i][j] = (floatx4){0.f,0.f,0.f,0.f};
  #pragma unroll
  for (int kh=0;kh<2;++kh){
    bf16x8 af[4], bfr[4];
    #pragma unroll
    for (int i=0;i<4;++i) af[i]  = *(const bf16x8*)&Tb[swz(i*16+fr, kh*32+fq*8)];
    #pragma unroll
    for (int j=0;j<4;++j) bfr[j] = *(const bf16x8*)&Bt[swz(j*16+fr, kh*32+fq*8)];
    #pragma unroll
    for (int i=0;i<4;++i)
      #pragma unroll
      for (int j=0;j<4;++j)
        acc[i][j] = __builtin_amdgcn_mfma_f32_16x16x32_bf16(af[i], bfr[j], acc[i][j], 0, 0, 0);
  }
  {
    const float* ibase = pinit + ((size_t)c*BH + bh)*4096;
    #pragma unroll
    for (int kh=0;kh<2;++kh){
      bf16x8 qs[4], inf[4];
      #pragma unroll
      for (int i=0;i<4;++i){
        const float sc = Dtl[i*16+fr];
        #pragma unroll
        for (int e=0;e<8;++e) qs[i][e] = (__bf16)(sc * (float)qf[i][kh][e]);
      }
      #pragma unroll
      for (int j=0;j<4;++j){
        const float* ip = ibase + (j*16+fr)*64 + kh*32 + fq*8;
        float4 f0 = *(const float4*)ip;
        float4 f1 = *(const float4*)(ip+4);
        inf[j][0]=(__bf16)f0.x; inf[j][1]=(__bf16)f0.y; inf[j][2]=(__bf16)f0.z; inf[j][3]=(__bf16)f0.w;
        inf[j][4]=(__bf16)f1.x; inf[j][5]=(__bf16)f1.y; inf[j][6]=(__bf16)f1.z; inf[j][7]=(__bf16)f1.w;
      }
      #pragma unroll
      for (int i=0;i<4;++i)
        #pragma unroll
        for (int j=0;j<4;++j)
          acc[i][j] = __builtin_amdgcn_mfma_f32_16x16x32_bf16(qs[i], inf[j], acc[i][j], 0, 0, 0);
    }
  }
  __syncthreads();
  #pragma unroll
  for (int i=0;i<4;++i)
    #pragma unroll
    for (int j=0;j<4;++j)
      #pragma unroll
      for (int r=0;r<4;++r)
        Tb[swz(i*16+fq*4+r, j*16+fr)] = f2bf(acc[i][j][r]);
  __syncthreads();
  {
    const unsigned short* qrow = proj + ((size_t)(b*S_+trow))*2048 + 1536 + h*64;
    unsigned short* orow = lcqr + ((size_t)(b*S_+trow))*512 + h*64;
    #pragma unroll
    for (int e8=0;e8<8;++e8){
      bf16x8 lcv = *(const bf16x8*)&Tb[swz(l, e8*8)];
      ushort4 q0 = *(const ushort4*)(qrow + e8*8);
      ushort4 q1 = *(const ushort4*)(qrow + e8*8 + 4);
      unsigned short qv[8] = {q0.x,q0.y,q0.z,q0.w,q1.x,q1.y,q1.z,q1.w};
      ushort4 o0, o1;
      o0.x = f2bf((float)lcv[0]*bf2f(qv[0]));
      o0.y = f2bf((float)lcv[1]*bf2f(qv[1]));
      o0.z = f2bf((float)lcv[2]*bf2f(qv[2]));
      o0.w = f2bf((float)lcv[3]*bf2f(qv[3]));
      o1.x = f2bf((float)lcv[4]*bf2f(qv[4]));
      o1.y = f2bf((float)lcv[5]*bf2f(qv[5]));
      o1.z = f2bf((float)lcv[6]*bf2f(qv[6]));
      o1.w = f2bf((float)lcv[7]*bf2f(qv[7]));
      *(ushort4*)(orow + e8*8)     = o0;
      *(ushort4*)(orow + e8*8 + 4) = o1;
    }
  }
}

// ---------- launch ----------
extern "C" void kernel_launch(void* const* d_in, const int* in_sizes, int n_in,
                              void* d_out, int out_size, void* d_ws, size_t ws_size,
                              hipStream_t stream){
  (void)in_sizes; (void)n_in; (void)out_size; (void)ws_size;
  const float* x    = (const float*)d_in[0];
  const float* ng   = (const float*)d_in[1];
  const float* nb   = (const float*)d_in[2];
  const float* fng  = (const float*)d_in[3];
  const float* fnb  = (const float*)d_in[4];
  const float* Wa   = (const float*)d_in[5];
  const float* Wb   = (const float*)d_in[6];
  const float* Wql  = (const float*)d_in[7];
  const float* Wqr  = (const float*)d_in[8];
  const float* Wsd  = (const float*)d_in[9];
  const float* bsd  = (const float*)d_in[10];
  const float* Wpd  = (const float*)d_in[11];
  const float* bpd  = (const float*)d_in[12];
  const float* Wout = (const float*)d_in[13];
  const float* W1   = (const float*)d_in[14];
  const float* b1   = (const float*)d_in[15];
  const float* W2   = (const float*)d_in[16];
  const float* b2   = (const float*)d_in[17];
  float* out = (float*)d_out;
  char* ws = (char*)d_ws;

  size_t off = 0;
  auto alloc = [&](size_t bytes)->char*{ char* p = ws + off; off += (bytes + 255) & ~(size_t)255; return p; };
  char* RA = alloc((size_t)ROWS*DM_*2);      // nbf -> lcqr -> nr
  char* RB = alloc((size_t)ROWS*2048*2);     // proj -> hbuf
  char* RD = alloc((size_t)BH*S_*64*4);      // slocb(bf16,front) -> pairb(f32,full)
  char* RE = alloc((size_t)BH*S_*64*4);      // prevb(bf16) -> rbufb(bf16)
  float* sdo   = (float*)alloc((size_t)ROWS*8*4);
  float* pdo   = (float*)alloc((size_t)ROWS*8*4);
  float* Sarr  = (float*)alloc((size_t)BH*S_*4);
  float* sinit = (float*)alloc((size_t)NCHUNK*BH*64*4);
  float* sEnd  = (float*)alloc((size_t)NCHUNK*BH*64*4);
  float* dprod = (float*)alloc((size_t)NCHUNK*BH*4);
  unsigned short* wcat  = (unsigned short*)alloc((size_t)2048*512*2);
  unsigned short* woutb = (unsigned short*)alloc((size_t)512*512*2);
  unsigned short* w1b   = (unsigned short*)alloc((size_t)2048*512*2);
  unsigned short* w2b   = (unsigned short*)alloc((size_t)512*2048*2);

  unsigned short* nbf   = (unsigned short*)RA;
  unsigned short* lcqr  = (unsigned short*)RA;
  unsigned short* nr    = (unsigned short*)RA;
  unsigned short* proj  = (unsigned short*)RB;
  unsigned short* hbuf  = (unsigned short*)RB;
  unsigned short* slocb = (unsigned short*)RD;
  float* pairb = (float*)RD;
  unsigned short* prevb = (unsigned short*)RE;
  unsigned short* rbufb = (unsigned short*)RE;

  cvt_weights<<<dim3(3328), dim3(256), 0, stream>>>(Wa,Wb,Wql,Wqr,Wout,W1,W2, wcat,woutb,w1b,w2b);
  ln_gates<<<dim3(ROWS), dim3(64), 0, stream>>>(x, ng, nb, Wsd, bsd, Wpd, bpd, nbf, sdo, pdo);
  // A/B: proj uses double-buffered variant, FFN1 (same shape) uses plain variant
  gemm128db<0><<<dim3(128,16), dim3(256), 0, stream>>>(nbf, wcat, proj, 2048, 512);
  state_local<<<dim3(NCHUNK,BH), dim3(64), 0, stream>>>(proj, sdo, slocb, Sarr, sEnd);
  state_combine<<<dim3(BH), dim3(64), 0, stream>>>(sEnd, Sarr, sinit);
  prev_mat<<<dim3(32768), dim3(256), 0, stream>>>(slocb, Sarr, sinit, prevb);
  pair_localm<<<dim3(NCHUNK,BH), dim3(64), 0, stream>>>(proj, pdo, prevb, pairb, dprod);
  pair_combine<<<dim3(1024), dim3(256), 0, stream>>>(pairb, dprod);
  pair_finalm<<<dim3(NCHUNK,BH), dim3(64), 0, stream>>>(proj, pdo, prevb, pairb, lcqr);
  gemm128<1><<<dim3(128,4), dim3(256), 0, stream>>>(lcqr, woutb, nullptr, x, nullptr, nullptr, rbufb, 512, 512);
  ln_plain<<<dim3(ROWS), dim3(64), 0, stream>>>(rbufb, fng, fnb, nr);
  gemm128<2><<<dim3(128,16), dim3(256), 0, stream>>>(nr, w1b, b1, nullptr, nullptr, nullptr, hbuf, 2048, 512);
  gemm128<3><<<dim3(128,4), dim3(256), 0, stream>>>(hbuf, w2b, b2, nullptr, rbufb, out, nullptr, 512, 2048);
}